// Round 1
// baseline (404.260 us; speedup 1.0000x reference)
//
#include <hip/hip_runtime.h>

// Problem constants (fixed by reference): feature_map (8,14,72,96,96) f32,
// landmarks (8,14,3) f32, R=20, output = scalar mean-over-(B*Lm) of summed BCE.
#define LZ 72
#define HX 96
#define WY 96
#define NBL 112            // 8*14
#define R2 400             // R^2
#define PLANE_F4 (HX * WY / 4)   // 2304 float4 per z-plane
#define ITERS (PLANE_F4 / 256)   // 9 per thread

// gt[z,x,y] = ((z-Z)^2 + (x-X)^2 + (y-Y)^2 <= R^2) where
// X=rint(lm0*95), Y=rint(lm1*95), Z=rint(lm2*71)  (rint = round-half-even, matches jnp.round)
// bce = max(v,0) - v*gt + log1p(exp(-|v|)); accumulate sum.

__global__ __launch_bounds__(256) void bce_partial_kernel(
    const float* __restrict__ fm,      // (NBL, LZ, HX, WY) flattened
    const float* __restrict__ lm,      // (NBL, 3)
    double* __restrict__ partial)      // (NBL * LZ) block partials
{
    const int z   = blockIdx.x;        // 0..71
    const int bl  = blockIdx.y;        // 0..111
    const int tid = threadIdx.x;

    // Landmark -> integer center (uniform across block; scalar-cached loads)
    const float l0 = lm[bl * 3 + 0];
    const float l1 = lm[bl * 3 + 1];
    const float l2 = lm[bl * 3 + 2];
    const int X = (int)__builtin_rintf(l0 * (HX - 1));
    const int Y = (int)__builtin_rintf(l1 * (WY - 1));
    const int Z = (int)__builtin_rintf(l2 * (LZ - 1));
    const int dz  = z - Z;
    const int dz2 = dz * dz;

    const float4* __restrict__ src = (const float4*)(
        fm + (size_t)bl * (LZ * HX * WY) + (size_t)z * (HX * WY));

    float acc = 0.0f;
#pragma unroll
    for (int i = 0; i < ITERS; ++i) {
        const int idx4 = tid + i * 256;        // 0..2303
        const float4 v = src[idx4];
        const int row = idx4 / 24;             // x coordinate (24 float4 per row)
        const int y0  = (idx4 - row * 24) * 4; // y base of this float4
        const int dx  = row - X;
        const int base = dz2 + dx * dx;

        const float xs[4] = {v.x, v.y, v.z, v.w};
#pragma unroll
        for (int j = 0; j < 4; ++j) {
            const int dy = y0 + j - Y;
            const float x  = xs[j];
            const float ax = fabsf(x);
            // softplus tail: log1p(exp(-|x|)); |err| < 1e-7 absolute, fine for f32-sum tolerance
            const float sp = fmaxf(x, 0.0f) + __logf(1.0f + __expf(-ax));
            const bool gt = (base + dy * dy) <= R2;
            acc += gt ? (sp - x) : sp;
        }
    }

    // wave64 butterfly-free down-reduce
#pragma unroll
    for (int off = 32; off > 0; off >>= 1)
        acc += __shfl_down(acc, off, 64);

    __shared__ double wsum[4];
    const int wave = tid >> 6;
    if ((tid & 63) == 0) wsum[wave] = (double)acc;
    __syncthreads();
    if (tid == 0) {
        const double s = wsum[0] + wsum[1] + wsum[2] + wsum[3];
        partial[(size_t)bl * gridDim.x + z] = s;
    }
}

__global__ __launch_bounds__(256) void bce_final_kernel(
    const double* __restrict__ partial, int n, float* __restrict__ out)
{
    double acc = 0.0;
    for (int i = threadIdx.x; i < n; i += 256) acc += partial[i];
#pragma unroll
    for (int off = 32; off > 0; off >>= 1)
        acc += __shfl_down(acc, off, 64);

    __shared__ double wsum[4];
    const int wave = threadIdx.x >> 6;
    if ((threadIdx.x & 63) == 0) wsum[wave] = acc;
    __syncthreads();
    if (threadIdx.x == 0) {
        const double s = wsum[0] + wsum[1] + wsum[2] + wsum[3];
        out[0] = (float)(s / (double)NBL);
    }
}

extern "C" void kernel_launch(void* const* d_in, const int* in_sizes, int n_in,
                              void* d_out, int out_size, void* d_ws, size_t ws_size,
                              hipStream_t stream) {
    const float* fm = (const float*)d_in[0];   // feature_map, 74,317,824 f32
    const float* lm = (const float*)d_in[1];   // landmarks, 336 f32
    float* out = (float*)d_out;                // 1 f32
    double* partial = (double*)d_ws;           // 8064 doubles = 64.5 KB scratch

    dim3 grid(LZ, NBL);                        // 72 x 112 = 8064 blocks
    bce_partial_kernel<<<grid, dim3(256), 0, stream>>>(fm, lm, partial);
    bce_final_kernel<<<1, dim3(256), 0, stream>>>(partial, LZ * NBL, out);
}

// Round 2
// 377.174 us; speedup vs baseline: 1.0718x; 1.0718x over previous
//
#include <hip/hip_runtime.h>

// feature_map (8,14,72,96,96) f32, landmarks (8,14,3) f32, R=20.
// out = sum(max(x,0) - x*gt + log1p(exp(-|x|))) / (B*Lm)
// gt[z,x,y] = ((z-Z)^2+(x-X)^2+(y-Y)^2 <= R^2), X=rint(lm0*95), Y=rint(lm1*95), Z=rint(lm2*71)
#define LZ 72
#define HX 96
#define WY 96
#define NBL 112            // 8*14
#define R2 400
#define PLANE_F4 (HX * WY / 4)   // 2304 float4 per z-plane
#define ITERS (PLANE_F4 / 256)   // 9 per thread

typedef __attribute__((ext_vector_type(4))) float f32x4;

__global__ __launch_bounds__(256) void bce_partial_kernel(
    const float* __restrict__ fm,      // (NBL, LZ, HX, WY)
    const float* __restrict__ lm,      // (NBL, 3)
    double* __restrict__ partial)      // (NBL * LZ)
{
    const int z   = blockIdx.x;        // 0..71
    const int bl  = blockIdx.y;        // 0..111
    const int tid = threadIdx.x;

    const float l0 = lm[bl * 3 + 0];
    const float l1 = lm[bl * 3 + 1];
    const float l2 = lm[bl * 3 + 2];
    const int X = (int)__builtin_rintf(l0 * (HX - 1));
    const int Y = (int)__builtin_rintf(l1 * (WY - 1));
    const int Z = (int)__builtin_rintf(l2 * (LZ - 1));
    const int dz2 = (z - Z) * (z - Z);

    const f32x4* __restrict__ src = (const f32x4*)(
        fm + (size_t)bl * (LZ * HX * WY) + (size_t)z * (HX * WY));

    // Phase 1: issue all loads (9 x dwordx4 nontemporal = 144 B/lane in flight)
    f32x4 v[ITERS];
#pragma unroll
    for (int i = 0; i < ITERS; ++i)
        v[i] = __builtin_nontemporal_load(src + (tid + i * 256));

    // Phase 2: compute
    float acc = 0.0f;
#pragma unroll
    for (int i = 0; i < ITERS; ++i) {
        const int idx4 = tid + i * 256;        // 0..2303
        const int row  = idx4 / 24;            // x coord (24 float4 per 96-wide row)
        const int dy0  = (idx4 - row * 24) * 4 - Y;
        const int dx   = row - X;
        const int base = dz2 + dx * dx;
#pragma unroll
        for (int j = 0; j < 4; ++j) {
            const int  dy = dy0 + j;
            const float x  = v[i][j];
            const float ax = fabsf(x);
            const float sp = fmaxf(x, 0.0f) + __logf(1.0f + __expf(-ax));
            const bool  gt = (base + dy * dy) <= R2;
            acc += gt ? (sp - x) : sp;
        }
    }

#pragma unroll
    for (int off = 32; off > 0; off >>= 1)
        acc += __shfl_down(acc, off, 64);

    __shared__ double wsum[4];
    const int wave = tid >> 6;
    if ((tid & 63) == 0) wsum[wave] = (double)acc;
    __syncthreads();
    if (tid == 0)
        partial[(size_t)bl * gridDim.x + z] = wsum[0] + wsum[1] + wsum[2] + wsum[3];
}

__global__ __launch_bounds__(256) void bce_final_kernel(
    const double* __restrict__ partial, int n, float* __restrict__ out)
{
    double acc = 0.0;
    for (int i = threadIdx.x; i < n; i += 256) acc += partial[i];
#pragma unroll
    for (int off = 32; off > 0; off >>= 1)
        acc += __shfl_down(acc, off, 64);

    __shared__ double wsum[4];
    const int wave = threadIdx.x >> 6;
    if ((threadIdx.x & 63) == 0) wsum[wave] = acc;
    __syncthreads();
    if (threadIdx.x == 0)
        out[0] = (float)((wsum[0] + wsum[1] + wsum[2] + wsum[3]) / (double)NBL);
}

extern "C" void kernel_launch(void* const* d_in, const int* in_sizes, int n_in,
                              void* d_out, int out_size, void* d_ws, size_t ws_size,
                              hipStream_t stream) {
    const float* fm = (const float*)d_in[0];
    const float* lm = (const float*)d_in[1];
    float* out = (float*)d_out;
    double* partial = (double*)d_ws;           // 8064 doubles = 64.5 KB

    dim3 grid(LZ, NBL);                        // 72 x 112 blocks
    bce_partial_kernel<<<grid, dim3(256), 0, stream>>>(fm, lm, partial);
    bce_final_kernel<<<1, dim3(256), 0, stream>>>(partial, LZ * NBL, out);
}